// Round 6
// baseline (168.986 us; speedup 1.0000x reference)
//
#include <hip/hip_runtime.h>
#include <hip/hip_bf16.h>
#include <stdint.h>

#define D 128
#define MCOLS 196      // 14*14
#define XPITCH 224     // xc pitch (bf16): 196 data + 28 zero K-pad, 16B-aligned rows
#define BPITCH 136     // NS buffer pitch; 16B-aligned rows
#define KOUT 8256      // 128*129/2

typedef short v8s __attribute__((ext_vector_type(8)));
typedef float v4f __attribute__((ext_vector_type(4)));

__device__ __forceinline__ uint32_t cvtpk(float a, float b) {
    __hip_bfloat162 h = __float22bfloat162_rn(make_float2(a, b));   // v_cvt_pk_bf16_f32
    uint32_t u;
    __builtin_memcpy(&u, &h, 4);
    return u;
}
__device__ __forceinline__ uint64_t pk64(float a, float b, float c, float d) {
    return (uint64_t)cvtpk(a, b) | ((uint64_t)cvtpk(c, d) << 32);
}
__device__ __forceinline__ float unlo(uint32_t u) { return __builtin_bit_cast(float, u << 16); }
__device__ __forceinline__ float unhi(uint32_t u) { return __builtin_bit_cast(float, u & 0xFFFF0000u); }

// Barrier WITHOUT vmcnt drain: keeps prefetch global_loads in flight across
// LDS-ordering barriers. lgkmcnt(0) orders all LDS ops; sched_barrier(0)
// prevents post-barrier ds ops hoisting above s_barrier.
__device__ __forceinline__ void barrier_nd() {
    asm volatile("s_waitcnt lgkmcnt(0)" ::: "memory");
    __builtin_amdgcn_s_barrier();
    __builtin_amdgcn_sched_barrier(0);
}

// Persistent: grid=256 (1 block/CU), 4 batches per block, input of batch k+1
// register-prefetched during batch k's NS chain. 512 threads = 8 waves (2/SIMD,
// 256-VGPR budget -> no spills). Wave grid 2x4: each wave owns 64x32 (4x2 tiles).
// All NS matrices symmetric -> one row-major LDS copy serves both MFMA operands.
// M = c*I + R split (c exact scalar); linear terms from per-wave register copies
// (Y1/ZY1/Y2 in f32, covM own-region packed bf16). covM stored UNNORMALIZED
// (1/tr folded into f32 combine scalars) -> trace barrier merges with cov barrier.
__global__ __launch_bounds__(512, 2) void mpncov_kernel(const float* __restrict__ x,
                                                        float* __restrict__ out) {
    __shared__ __align__(16) uint16_t lds[4 * D * BPITCH];   // 139264 B
    __shared__ float redbuf[8];

    uint16_t* const B0 = lds;
    uint16_t* const B1 = lds + 1 * D * BPITCH;
    uint16_t* const B2 = lds + 2 * D * BPITCH;
    uint16_t* const B3 = lds + 3 * D * BPITCH;
    // xc (128 x 224 bf16 = 57344 B) overlays B1+B2 (69632 B). Rotation:
    // covM=B0, Y1=B1, ZY1=B2, Y2=B3, Z2=B1, T2=B0 -> B2 dead after MM4,
    // B1 dead after MM5 -> pack(k+1) runs during MM6.
    uint16_t (*const xc)[XPITCH] = reinterpret_cast<uint16_t(*)[XPITCH]>(B1);

    const int tid = threadIdx.x;
    const int lane = tid & 63;
    const int w = tid >> 6, wr = w >> 2, wc = w & 3;   // 2x4 wave grid
    const int lr = lane & 15, lk = lane >> 4;
    const int pr = tid >> 2, pq = tid & 3;             // prefetch: 4 threads/row

    // ---- cross-batch prefetch state: 49 float4 per row, 12(+1 tail) per thread ----
    float4 pf[12]; float4 pfT;
    uint64_t pk[12]; uint64_t pkT;

    auto issue_pf = [&](int bbn) {
        const float4* p4 = reinterpret_cast<const float4*>(x + (size_t)bbn * (D * MCOLS)) + 49 * pr;
#pragma unroll
        for (int i = 0; i < 12; ++i) pf[i] = p4[pq + 4 * i];
        if (pq == 0) pfT = p4[48];
    };
    auto cvt_pf = [&]() {   // row mean via 4-lane shfl, center exactly in f32, pack bf16
        float s = 0.f;
#pragma unroll
        for (int i = 0; i < 12; ++i) s += (pf[i].x + pf[i].y) + (pf[i].z + pf[i].w);
        if (pq == 0) s += (pfT.x + pfT.y) + (pfT.z + pfT.w);
        s += __shfl_xor(s, 1); s += __shfl_xor(s, 2);
        const float m = s * (1.0f / MCOLS);
#pragma unroll
        for (int i = 0; i < 12; ++i)
            pk[i] = pk64(pf[i].x - m, pf[i].y - m, pf[i].z - m, pf[i].w - m);
        if (pq == 0) pkT = pk64(pfT.x - m, pfT.y - m, pfT.z - m, pfT.w - m);
    };
    auto pack_pf = [&]() {   // scatter packed bf16 to xc + zero K-pad (cols 196..223)
#pragma unroll
        for (int i = 0; i < 12; ++i)
            *reinterpret_cast<uint64_t*>(&xc[pr][4 * (pq + 4 * i)]) = pk[i];
        if (pq == 0) *reinterpret_cast<uint64_t*>(&xc[pr][192]) = pkT;
        *reinterpret_cast<uint64_t*>(&xc[pr][MCOLS + 4 * pq]) = 0ull;
        if (pq < 3) *reinterpret_cast<uint64_t*>(&xc[pr][MCOLS + 4 * (pq + 4)]) = 0ull;
    };

    v4f acc[4][2];
    auto zacc = [&]() {
#pragma unroll
        for (int i = 0; i < 4; ++i)
#pragma unroll
            for (int j = 0; j < 2; ++j) acc[i][j] = v4f{0.f, 0.f, 0.f, 0.f};
    };
    auto matmul = [&](const uint16_t* P, const uint16_t* Q) {
        zacc();
#pragma unroll
        for (int kk = 0; kk < 4; ++kk) {
            const int k0 = kk * 32 + lk * 8;
            v8s af[4], bf[2];
#pragma unroll
            for (int i = 0; i < 4; ++i)
                af[i] = *reinterpret_cast<const v8s*>(&P[(64 * wr + 16 * i + lr) * BPITCH + k0]);
#pragma unroll
            for (int j = 0; j < 2; ++j)
                bf[j] = *reinterpret_cast<const v8s*>(&Q[(32 * wc + 16 * j + lr) * BPITCH + k0]);
#pragma unroll
            for (int i = 0; i < 4; ++i)
#pragma unroll
                for (int j = 0; j < 2; ++j)
                    acc[i][j] = __builtin_amdgcn_mfma_f32_16x16x32_bf16(af[i], bf[j], acc[i][j], 0, 0, 0);
        }
    };
    auto store42 = [&](uint16_t* dst, const v4f (&mm)[4][2]) {   // symmetric: store transposed
#pragma unroll
        for (int i = 0; i < 4; ++i) {
            const int r0 = 64 * wr + 16 * i + 4 * lk;
#pragma unroll
            for (int j = 0; j < 2; ++j) {
                const int c = 32 * wc + 16 * j + lr;
                *reinterpret_cast<uint64_t*>(&dst[c * BPITCH + r0]) =
                    pk64(mm[i][j][0], mm[i][j][1], mm[i][j][2], mm[i][j][3]);
            }
        }
    };

    v4f regY1[4][2], regZY1[4][2], regY2[4][2];
    uint32_t regCp[4][2][2];   // own-region covM, packed bf16 (2 words per tile-quad)

    // ---- prologue: stage batch (4*blockIdx.x) ----
    issue_pf(4 * blockIdx.x);
    cvt_pf();
    pack_pf();

    for (int it = 0; it < 4; ++it) {
        const int bb = 4 * blockIdx.x + it;
        barrier_nd();                               // xc(bb) ready

        if (it < 3) {                               // issue next batch's loads NOW;
            issue_pf(bb + 1);                       // they stay in flight across all
            __builtin_amdgcn_sched_barrier(0);      // no-drain barriers below
        }

        // ---- cov: covM = xc @ xc^T (centered, K padded to 224) ----
        zacc();
#pragma unroll
        for (int kk = 0; kk < 7; ++kk) {
            const int k0 = kk * 32 + lk * 8;
            v8s af[4], bf[2];
#pragma unroll
            for (int i = 0; i < 4; ++i)
                af[i] = *reinterpret_cast<const v8s*>(&xc[64 * wr + 16 * i + lr][k0]);
#pragma unroll
            for (int j = 0; j < 2; ++j)
                bf[j] = *reinterpret_cast<const v8s*>(&xc[32 * wc + 16 * j + lr][k0]);
#pragma unroll
            for (int i = 0; i < 4; ++i)
#pragma unroll
                for (int j = 0; j < 2; ++j)
                    acc[i][j] = __builtin_amdgcn_mfma_f32_16x16x32_bf16(af[i], bf[j], acc[i][j], 0, 0, 0);
        }

        // trace (C/D layout: col=lane&15, row=(lane>>4)*4+q)
        float tval = 0.f;
        if ((lr >> 2) == lk) {
            const int qq = lr & 3;
#pragma unroll
            for (int i = 0; i < 4; ++i)
#pragma unroll
                for (int j = 0; j < 2; ++j)
                    if (4 * wr + i == 2 * wc + j) tval += acc[i][j][qq];
        }
#pragma unroll
        for (int off = 32; off; off >>= 1) tval += __shfl_down(tval, off);
        if (lane == 0) redbuf[w] = tval;

        // store covM (unnormalized) + keep own region as packed bf16
#pragma unroll
        for (int i = 0; i < 4; ++i) {
            const int r0 = 64 * wr + 16 * i + 4 * lk;
#pragma unroll
            for (int j = 0; j < 2; ++j) {
                const int c = 32 * wc + 16 * j + lr;
                regCp[i][j][0] = cvtpk(acc[i][j][0], acc[i][j][1]);
                regCp[i][j][1] = cvtpk(acc[i][j][2], acc[i][j][3]);
                *reinterpret_cast<uint64_t*>(&B0[c * BPITCH + r0]) =
                    (uint64_t)regCp[i][j][0] | ((uint64_t)regCp[i][j][1] << 32);
            }
        }
        barrier_nd();                               // covM + redbuf visible; xc dead

        const float tr = ((redbuf[0] + redbuf[1]) + (redbuf[2] + redbuf[3])) +
                         ((redbuf[4] + redbuf[5]) + (redbuf[6] + redbuf[7]));
        const float inv = 1.0f / tr;
        const float outscale = sqrtf(tr * (1.0f / MCOLS));
        const float s11 = -0.5f * inv * inv, s12 = 1.5f * inv;
        const float s21 = 0.25f * inv;
        const float s41 = -0.5f * inv, s42 = -0.75f * inv;

        // MM1: RY1 = -0.5*inv^2*(C@C) + 1.5*inv*C
        matmul(B0, B0);
#pragma unroll
        for (int i = 0; i < 4; ++i)
#pragma unroll
            for (int j = 0; j < 2; ++j) {
                const float c0 = unlo(regCp[i][j][0]), c1 = unhi(regCp[i][j][0]);
                const float c2 = unlo(regCp[i][j][1]), c3 = unhi(regCp[i][j][1]);
                regY1[i][j] = v4f{s11 * acc[i][j][0] + s12 * c0, s11 * acc[i][j][1] + s12 * c1,
                                  s11 * acc[i][j][2] + s12 * c2, s11 * acc[i][j][3] + s12 * c3};
            }
        store42(B1, regY1);
        barrier_nd();

        // MM2: RZY1 = 0.25*inv*(C@RY1) - 0.75*RY1
        matmul(B0, B1);
#pragma unroll
        for (int i = 0; i < 4; ++i)
#pragma unroll
            for (int j = 0; j < 2; ++j)
#pragma unroll
                for (int q = 0; q < 4; ++q)
                    regZY1[i][j][q] = s21 * acc[i][j][q] - 0.75f * regY1[i][j][q];
        store42(B2, regZY1);
        barrier_nd();

        // MM3: RY2 = RY1@RZY1 + 1.5*RY1   [RY1 dead after]
        matmul(B1, B2);
#pragma unroll
        for (int i = 0; i < 4; ++i)
#pragma unroll
            for (int j = 0; j < 2; ++j)
#pragma unroll
                for (int q = 0; q < 4; ++q)
                    regY2[i][j][q] = acc[i][j][q] + 1.5f * regY1[i][j][q];
        store42(B3, regY2);
        barrier_nd();

        // MM4: RZ2 = -0.5*inv*(RZY1@C) - 0.75*inv*C + 1.5*RZY1  [covM,ZY1,Cp dead after]
        matmul(B2, B0);
        {
            v4f z2[4][2];
#pragma unroll
            for (int i = 0; i < 4; ++i)
#pragma unroll
                for (int j = 0; j < 2; ++j) {
                    const float c0 = unlo(regCp[i][j][0]), c1 = unhi(regCp[i][j][0]);
                    const float c2 = unlo(regCp[i][j][1]), c3 = unhi(regCp[i][j][1]);
                    z2[i][j] = v4f{s41 * acc[i][j][0] + s42 * c0 + 1.5f * regZY1[i][j][0],
                                   s41 * acc[i][j][1] + s42 * c1 + 1.5f * regZY1[i][j][1],
                                   s41 * acc[i][j][2] + s42 * c2 + 1.5f * regZY1[i][j][2],
                                   s41 * acc[i][j][3] + s42 * c3 + 1.5f * regZY1[i][j][3]};
                }
            store42(B1, z2);                       // Z2 -> B1 (Y1 slot)
        }
        barrier_nd();

        // MM5: RT2 = RZ2@RY2 + 2.25*RY2
        matmul(B1, B3);
        {
            v4f t2[4][2];
#pragma unroll
            for (int i = 0; i < 4; ++i)
#pragma unroll
                for (int j = 0; j < 2; ++j)
#pragma unroll
                    for (int q = 0; q < 4; ++q)
                        t2[i][j][q] = acc[i][j][q] + 2.25f * regY2[i][j][q];
            store42(B0, t2);                       // T2 -> B0 (covM slot)
        }
        if (it < 3) cvt_pf();                      // loads long since landed; pf -> pk
        barrier_nd();                              // T2 ready; B1,B2 (=xc region) dead

        // MM6: O = (1.5*RY2 - 0.5*(RY2@RT2)) * outscale ; upper-tri only
        if (!(wr == 1 && wc < 2)) {
            zacc();
#pragma unroll
            for (int kk = 0; kk < 4; ++kk) {
                const int k0 = kk * 32 + lk * 8;
                v8s af[4], bf[2];
#pragma unroll
                for (int i = 0; i < 4; ++i)
                    af[i] = *reinterpret_cast<const v8s*>(&B3[(64 * wr + 16 * i + lr) * BPITCH + k0]);
#pragma unroll
                for (int j = 0; j < 2; ++j)
                    bf[j] = *reinterpret_cast<const v8s*>(&B0[(32 * wc + 16 * j + lr) * BPITCH + k0]);
#pragma unroll
                for (int i = 0; i < 4; ++i)
#pragma unroll
                    for (int j = 0; j < 2; ++j)
                        if (4 * wr + i <= 2 * wc + j)
                            acc[i][j] = __builtin_amdgcn_mfma_f32_16x16x32_bf16(af[i], bf[j], acc[i][j], 0, 0, 0);
            }
            float* ob = out + (size_t)bb * KOUT;
#pragma unroll
            for (int i = 0; i < 4; ++i) {
                const int r0 = 64 * wr + 16 * i + 4 * lk;
#pragma unroll
                for (int j = 0; j < 2; ++j) {
                    const int rb = 4 * wr + i, cb = 2 * wc + j;
                    if (rb > cb) continue;
                    const int c = 32 * wc + 16 * j + lr;
                    float vv[4];
#pragma unroll
                    for (int q = 0; q < 4; ++q)
                        vv[q] = (1.5f * regY2[i][j][q] - 0.5f * acc[i][j][q]) * outscale;
                    if (rb < cb) {
#pragma unroll
                        for (int q = 0; q < 4; ++q) {
                            const int r = r0 + q;
                            ob[r * D - (r * (r + 1)) / 2 + c] = vv[q];
                        }
                    } else {
#pragma unroll
                        for (int q = 0; q < 4; ++q) {
                            const int r = r0 + q;
                            if (r <= c) ob[r * D - (r * (r + 1)) / 2 + c] = vv[q];
                        }
                    }
                }
            }
        }
        if (it < 3) pack_pf();                     // xc(bb+1) into B1/B2, overlaps MM6
    }
}

extern "C" void kernel_launch(void* const* d_in, const int* in_sizes, int n_in,
                              void* d_out, int out_size, void* d_ws, size_t ws_size,
                              hipStream_t stream) {
    const float* x = (const float*)d_in[0];
    float* out = (float*)d_out;
    mpncov_kernel<<<dim3(256), dim3(512), 0, stream>>>(x, out);
}

// Round 7
// 139.967 us; speedup vs baseline: 1.2073x; 1.2073x over previous
//
#include <hip/hip_runtime.h>
#include <hip/hip_bf16.h>
#include <stdint.h>

#define D 128
#define MCOLS 196      // 14*14
#define XPITCH 224     // xc pitch (bf16): 196 data + 28 zero K-pad, 16B-aligned rows
#define BPITCH 136     // NS buffer pitch; 16B-aligned rows
#define KOUT 8256      // 128*129/2

typedef short v8s __attribute__((ext_vector_type(8)));
typedef float v4f __attribute__((ext_vector_type(4)));

__device__ __forceinline__ uint32_t cvtpk(float a, float b) {
    __hip_bfloat162 h = __float22bfloat162_rn(make_float2(a, b));   // v_cvt_pk_bf16_f32
    uint32_t u;
    __builtin_memcpy(&u, &h, 4);
    return u;
}
__device__ __forceinline__ uint64_t pk64(float a, float b, float c, float d) {
    return (uint64_t)cvtpk(a, b) | ((uint64_t)cvtpk(c, d) << 32);
}
__device__ __forceinline__ float unlo(uint32_t u) { return __builtin_bit_cast(float, u << 16); }
__device__ __forceinline__ float unhi(uint32_t u) { return __builtin_bit_cast(float, u & 0xFFFF0000u); }

// Barrier WITHOUT vmcnt drain: keeps prefetch global_loads in flight across
// LDS-ordering barriers. lgkmcnt(0) orders all LDS ops; sched_barrier(0)
// prevents post-barrier ds ops hoisting above s_barrier.
__device__ __forceinline__ void barrier_nd() {
    asm volatile("s_waitcnt lgkmcnt(0)" ::: "memory");
    __builtin_amdgcn_s_barrier();
    __builtin_amdgcn_sched_barrier(0);
}

// Persistent: grid=256 (1 block/CU), 4 batches per block, input of batch k+1
// register-prefetched during batch k's NS chain. 512 threads = 8 waves.
// amdgpu_waves_per_eu(2,2) pins EXACTLY 2 waves/SIMD -> 256-VGPR budget, no
// spills (launch_bounds' min-waves arg alone let LLVM spill toward 4 waves/EU).
// Wave grid 2x4: each wave owns 64x32 (4x2 16x16 tiles). All NS matrices
// symmetric -> one row-major LDS copy serves both MFMA operands. M = c*I + R
// split; linear terms from per-wave register copies (Y1/ZY1/Y2 f32, covM
// own-region packed bf16). covM stored UNNORMALIZED (1/tr folded into combines).
__global__ __attribute__((amdgpu_waves_per_eu(2, 2))) __launch_bounds__(512)
void mpncov_kernel(const float* __restrict__ x, float* __restrict__ out) {
    __shared__ __align__(16) uint16_t lds[4 * D * BPITCH];   // 139264 B
    __shared__ float redbuf[8];

    uint16_t* const B0 = lds;
    uint16_t* const B1 = lds + 1 * D * BPITCH;
    uint16_t* const B2 = lds + 2 * D * BPITCH;
    uint16_t* const B3 = lds + 3 * D * BPITCH;
    // xc (128 x 224 bf16 = 57344 B) overlays B1+B2 (69632 B). Rotation:
    // covM=B0, Y1=B1, ZY1=B2, Y2=B3, Z2=B1, T2=B0 -> B2 dead after MM4,
    // B1 dead after MM5 -> pack(k+1) runs during/after MM6.
    uint16_t (*const xc)[XPITCH] = reinterpret_cast<uint16_t(*)[XPITCH]>(B1);

    const int tid = threadIdx.x;
    const int lane = tid & 63;
    const int w = tid >> 6, wr = w >> 2, wc = w & 3;   // 2x4 wave grid
    const int lr = lane & 15, lk = lane >> 4;
    const int pr = tid >> 2, pq = tid & 3;             // prefetch: 4 threads/row

    // ---- cross-batch prefetch state: 49 float4 per row, 12(+1 tail) per thread ----
    float4 pf[12]; float4 pfT;

    auto issue_pf = [&](int bbn) {
        const float4* p4 = reinterpret_cast<const float4*>(x + (size_t)bbn * (D * MCOLS)) + 49 * pr;
#pragma unroll
        for (int i = 0; i < 12; ++i) pf[i] = p4[pq + 4 * i];
        if (pq == 0) pfT = p4[48];
    };
    // mean via 4-lane shfl, center exactly in f32, pack bf16, write xc + zero K-pad
    auto pack_pf = [&]() {
        float s = 0.f;
#pragma unroll
        for (int i = 0; i < 12; ++i) s += (pf[i].x + pf[i].y) + (pf[i].z + pf[i].w);
        if (pq == 0) s += (pfT.x + pfT.y) + (pfT.z + pfT.w);
        s += __shfl_xor(s, 1); s += __shfl_xor(s, 2);
        const float m = s * (1.0f / MCOLS);
#pragma unroll
        for (int i = 0; i < 12; ++i)
            *reinterpret_cast<uint64_t*>(&xc[pr][4 * (pq + 4 * i)]) =
                pk64(pf[i].x - m, pf[i].y - m, pf[i].z - m, pf[i].w - m);
        if (pq == 0)
            *reinterpret_cast<uint64_t*>(&xc[pr][192]) =
                pk64(pfT.x - m, pfT.y - m, pfT.z - m, pfT.w - m);
        *reinterpret_cast<uint64_t*>(&xc[pr][MCOLS + 4 * pq]) = 0ull;
        if (pq < 3) *reinterpret_cast<uint64_t*>(&xc[pr][MCOLS + 4 * (pq + 4)]) = 0ull;
    };

    v4f acc[4][2];
    auto zacc = [&]() {
#pragma unroll
        for (int i = 0; i < 4; ++i)
#pragma unroll
            for (int j = 0; j < 2; ++j) acc[i][j] = v4f{0.f, 0.f, 0.f, 0.f};
    };
    auto matmul = [&](const uint16_t* P, const uint16_t* Q) {
        zacc();
#pragma unroll
        for (int kk = 0; kk < 4; ++kk) {
            const int k0 = kk * 32 + lk * 8;
            v8s af[4], bf[2];
#pragma unroll
            for (int i = 0; i < 4; ++i)
                af[i] = *reinterpret_cast<const v8s*>(&P[(64 * wr + 16 * i + lr) * BPITCH + k0]);
#pragma unroll
            for (int j = 0; j < 2; ++j)
                bf[j] = *reinterpret_cast<const v8s*>(&Q[(32 * wc + 16 * j + lr) * BPITCH + k0]);
#pragma unroll
            for (int i = 0; i < 4; ++i)
#pragma unroll
                for (int j = 0; j < 2; ++j)
                    acc[i][j] = __builtin_amdgcn_mfma_f32_16x16x32_bf16(af[i], bf[j], acc[i][j], 0, 0, 0);
        }
    };
    auto store42 = [&](uint16_t* dst, const v4f (&mm)[4][2]) {   // symmetric: store transposed
#pragma unroll
        for (int i = 0; i < 4; ++i) {
            const int r0 = 64 * wr + 16 * i + 4 * lk;
#pragma unroll
            for (int j = 0; j < 2; ++j) {
                const int c = 32 * wc + 16 * j + lr;
                *reinterpret_cast<uint64_t*>(&dst[c * BPITCH + r0]) =
                    pk64(mm[i][j][0], mm[i][j][1], mm[i][j][2], mm[i][j][3]);
            }
        }
    };

    v4f regY1[4][2], regZY1[4][2], regY2[4][2];
    uint32_t regCp[4][2][2];   // own-region covM, packed bf16 (2 words per tile-quad)

    // ---- prologue: stage batch (4*blockIdx.x) ----
    issue_pf(4 * blockIdx.x);
    pack_pf();

    for (int it = 0; it < 4; ++it) {
        const int bb = 4 * blockIdx.x + it;
        barrier_nd();                               // xc(bb) ready

        if (it < 3) {                               // issue next batch's loads NOW;
            issue_pf(bb + 1);                       // they stay in flight across all
            __builtin_amdgcn_sched_barrier(0);      // no-drain barriers below
        }

        // ---- cov: covM = xc @ xc^T (centered, K padded to 224) ----
        zacc();
#pragma unroll
        for (int kk = 0; kk < 7; ++kk) {
            const int k0 = kk * 32 + lk * 8;
            v8s af[4], bf[2];
#pragma unroll
            for (int i = 0; i < 4; ++i)
                af[i] = *reinterpret_cast<const v8s*>(&xc[64 * wr + 16 * i + lr][k0]);
#pragma unroll
            for (int j = 0; j < 2; ++j)
                bf[j] = *reinterpret_cast<const v8s*>(&xc[32 * wc + 16 * j + lr][k0]);
#pragma unroll
            for (int i = 0; i < 4; ++i)
#pragma unroll
                for (int j = 0; j < 2; ++j)
                    acc[i][j] = __builtin_amdgcn_mfma_f32_16x16x32_bf16(af[i], bf[j], acc[i][j], 0, 0, 0);
        }

        // trace (C/D layout: col=lane&15, row=(lane>>4)*4+q)
        float tval = 0.f;
        if ((lr >> 2) == lk) {
            const int qq = lr & 3;
#pragma unroll
            for (int i = 0; i < 4; ++i)
#pragma unroll
                for (int j = 0; j < 2; ++j)
                    if (4 * wr + i == 2 * wc + j) tval += acc[i][j][qq];
        }
#pragma unroll
        for (int off = 32; off; off >>= 1) tval += __shfl_down(tval, off);
        if (lane == 0) redbuf[w] = tval;

        // store covM (unnormalized) + keep own region as packed bf16
#pragma unroll
        for (int i = 0; i < 4; ++i) {
            const int r0 = 64 * wr + 16 * i + 4 * lk;
#pragma unroll
            for (int j = 0; j < 2; ++j) {
                const int c = 32 * wc + 16 * j + lr;
                regCp[i][j][0] = cvtpk(acc[i][j][0], acc[i][j][1]);
                regCp[i][j][1] = cvtpk(acc[i][j][2], acc[i][j][3]);
                *reinterpret_cast<uint64_t*>(&B0[c * BPITCH + r0]) =
                    (uint64_t)regCp[i][j][0] | ((uint64_t)regCp[i][j][1] << 32);
            }
        }
        barrier_nd();                               // covM + redbuf visible; xc dead

        const float tr = ((redbuf[0] + redbuf[1]) + (redbuf[2] + redbuf[3])) +
                         ((redbuf[4] + redbuf[5]) + (redbuf[6] + redbuf[7]));
        const float inv = 1.0f / tr;
        const float outscale = sqrtf(tr * (1.0f / MCOLS));
        const float s11 = -0.5f * inv * inv, s12 = 1.5f * inv;
        const float s21 = 0.25f * inv;
        const float s41 = -0.5f * inv, s42 = -0.75f * inv;

        // MM1: RY1 = -0.5*inv^2*(C@C) + 1.5*inv*C
        matmul(B0, B0);
#pragma unroll
        for (int i = 0; i < 4; ++i)
#pragma unroll
            for (int j = 0; j < 2; ++j) {
                const float c0 = unlo(regCp[i][j][0]), c1 = unhi(regCp[i][j][0]);
                const float c2 = unlo(regCp[i][j][1]), c3 = unhi(regCp[i][j][1]);
                regY1[i][j] = v4f{s11 * acc[i][j][0] + s12 * c0, s11 * acc[i][j][1] + s12 * c1,
                                  s11 * acc[i][j][2] + s12 * c2, s11 * acc[i][j][3] + s12 * c3};
            }
        store42(B1, regY1);
        barrier_nd();

        // MM2: RZY1 = 0.25*inv*(C@RY1) - 0.75*RY1
        matmul(B0, B1);
#pragma unroll
        for (int i = 0; i < 4; ++i)
#pragma unroll
            for (int j = 0; j < 2; ++j)
#pragma unroll
                for (int q = 0; q < 4; ++q)
                    regZY1[i][j][q] = s21 * acc[i][j][q] - 0.75f * regY1[i][j][q];
        store42(B2, regZY1);
        barrier_nd();

        // MM3: RY2 = RY1@RZY1 + 1.5*RY1   [RY1 dead after]
        matmul(B1, B2);
#pragma unroll
        for (int i = 0; i < 4; ++i)
#pragma unroll
            for (int j = 0; j < 2; ++j)
#pragma unroll
                for (int q = 0; q < 4; ++q)
                    regY2[i][j][q] = acc[i][j][q] + 1.5f * regY1[i][j][q];
        store42(B3, regY2);
        barrier_nd();

        // MM4: RZ2 = -0.5*inv*(RZY1@C) - 0.75*inv*C + 1.5*RZY1  [covM,ZY1,Cp dead after]
        matmul(B2, B0);
        {
            v4f z2[4][2];
#pragma unroll
            for (int i = 0; i < 4; ++i)
#pragma unroll
                for (int j = 0; j < 2; ++j) {
                    const float c0 = unlo(regCp[i][j][0]), c1 = unhi(regCp[i][j][0]);
                    const float c2 = unlo(regCp[i][j][1]), c3 = unhi(regCp[i][j][1]);
                    z2[i][j] = v4f{s41 * acc[i][j][0] + s42 * c0 + 1.5f * regZY1[i][j][0],
                                   s41 * acc[i][j][1] + s42 * c1 + 1.5f * regZY1[i][j][1],
                                   s41 * acc[i][j][2] + s42 * c2 + 1.5f * regZY1[i][j][2],
                                   s41 * acc[i][j][3] + s42 * c3 + 1.5f * regZY1[i][j][3]};
                }
            store42(B1, z2);                       // Z2 -> B1 (Y1 slot)
        }
        barrier_nd();

        // MM5: RT2 = RZ2@RY2 + 2.25*RY2
        matmul(B1, B3);
        {
            v4f t2[4][2];
#pragma unroll
            for (int i = 0; i < 4; ++i)
#pragma unroll
                for (int j = 0; j < 2; ++j)
#pragma unroll
                    for (int q = 0; q < 4; ++q)
                        t2[i][j][q] = acc[i][j][q] + 2.25f * regY2[i][j][q];
            store42(B0, t2);                       // T2 -> B0 (covM slot)
        }
        barrier_nd();                              // T2 ready; B1,B2 (=xc region) dead

        // MM6: O = (1.5*RY2 - 0.5*(RY2@RT2)) * outscale ; upper-tri only
        if (!(wr == 1 && wc < 2)) {
            zacc();
#pragma unroll
            for (int kk = 0; kk < 4; ++kk) {
                const int k0 = kk * 32 + lk * 8;
                v8s af[4], bf[2];
#pragma unroll
                for (int i = 0; i < 4; ++i)
                    af[i] = *reinterpret_cast<const v8s*>(&B3[(64 * wr + 16 * i + lr) * BPITCH + k0]);
#pragma unroll
                for (int j = 0; j < 2; ++j)
                    bf[j] = *reinterpret_cast<const v8s*>(&B0[(32 * wc + 16 * j + lr) * BPITCH + k0]);
#pragma unroll
                for (int i = 0; i < 4; ++i)
#pragma unroll
                    for (int j = 0; j < 2; ++j)
                        if (4 * wr + i <= 2 * wc + j)
                            acc[i][j] = __builtin_amdgcn_mfma_f32_16x16x32_bf16(af[i], bf[j], acc[i][j], 0, 0, 0);
            }
            float* ob = out + (size_t)bb * KOUT;
#pragma unroll
            for (int i = 0; i < 4; ++i) {
                const int r0 = 64 * wr + 16 * i + 4 * lk;
#pragma unroll
                for (int j = 0; j < 2; ++j) {
                    const int rb = 4 * wr + i, cb = 2 * wc + j;
                    if (rb > cb) continue;
                    const int c = 32 * wc + 16 * j + lr;
                    float vv[4];
#pragma unroll
                    for (int q = 0; q < 4; ++q)
                        vv[q] = (1.5f * regY2[i][j][q] - 0.5f * acc[i][j][q]) * outscale;
                    if (rb < cb) {
#pragma unroll
                        for (int q = 0; q < 4; ++q) {
                            const int r = r0 + q;
                            ob[r * D - (r * (r + 1)) / 2 + c] = vv[q];
                        }
                    } else {
#pragma unroll
                        for (int q = 0; q < 4; ++q) {
                            const int r = r0 + q;
                            if (r <= c) ob[r * D - (r * (r + 1)) / 2 + c] = vv[q];
                        }
                    }
                }
            }
        }
        if (it < 3) pack_pf();                     // xc(bb+1) into B1/B2, overlaps MM6
    }
}

extern "C" void kernel_launch(void* const* d_in, const int* in_sizes, int n_in,
                              void* d_out, int out_size, void* d_ws, size_t ws_size,
                              hipStream_t stream) {
    const float* x = (const float*)d_in[0];
    float* out = (float*)d_out;
    mpncov_kernel<<<dim3(256), dim3(512), 0, stream>>>(x, out);
}

// Round 8
// 67.673 us; speedup vs baseline: 2.4971x; 2.0683x over previous
//
#include <hip/hip_runtime.h>
#include <hip/hip_bf16.h>
#include <stdint.h>

#define D 128
#define MCOLS 196      // 14*14
#define XPITCH 224     // xc pitch (bf16): 196 data + 28 zero K-pad, 16B-aligned rows
#define BPITCH 136     // NS buffer pitch; 16B-aligned rows
#define KOUT 8256      // 128*129/2

typedef short v8s __attribute__((ext_vector_type(8)));
typedef float v4f __attribute__((ext_vector_type(4)));

__device__ __forceinline__ uint32_t cvtpk(float a, float b) {
    __hip_bfloat162 h = __float22bfloat162_rn(make_float2(a, b));   // v_cvt_pk_bf16_f32
    uint32_t u;
    __builtin_memcpy(&u, &h, 4);
    return u;
}
__device__ __forceinline__ uint64_t pk64(float a, float b, float c, float d) {
    return (uint64_t)cvtpk(a, b) | ((uint64_t)cvtpk(c, d) << 32);
}
__device__ __forceinline__ float unlo(uint32_t u) { return __builtin_bit_cast(float, u << 16); }
__device__ __forceinline__ float unhi(uint32_t u) { return __builtin_bit_cast(float, u & 0xFFFF0000u); }

// Barrier WITHOUT vmcnt drain: keeps prefetch global_loads in flight across
// LDS-ordering barriers. lgkmcnt(0) orders all LDS ops; sched_barrier(0)
// prevents post-barrier ds ops hoisting above s_barrier.
__device__ __forceinline__ void barrier_nd() {
    asm volatile("s_waitcnt lgkmcnt(0)" ::: "memory");
    __builtin_amdgcn_s_barrier();
    __builtin_amdgcn_sched_barrier(0);
}

// Persistent: grid=256 (1 block/CU), 4 batches/block, batch k+1's input
// register-prefetched during batch k's NS chain (no-drain barriers keep the
// loads in flight). 512 threads = 8 waves, 2x4 wave grid, 64x32 per wave.
// REGISTER-LEAN: no f32 matrix copies. All linear terms c*R over the wave's
// own region are RELOADED from LDS (own region is contiguous b64 in the
// transposed-symmetric store). Live regs ~105 < 128 budget -> no spills.
// All NS matrices symmetric -> one row-major LDS copy serves both operands.
__global__ __launch_bounds__(512) void mpncov_kernel(const float* __restrict__ x,
                                                     float* __restrict__ out) {
    __shared__ __align__(16) uint16_t lds[4 * D * BPITCH];   // 139264 B
    __shared__ float redbuf[8];

    uint16_t* const B0 = lds;
    uint16_t* const B1 = lds + 1 * D * BPITCH;
    uint16_t* const B2 = lds + 2 * D * BPITCH;
    uint16_t* const B3 = lds + 3 * D * BPITCH;
    // xc (128 x 224 bf16 = 57344 B) overlays B1+B2 (69632 B). Rotation:
    // covM=B0, Y1=B1, ZY1=B2, Y2=B3, Z2=B1, T2=B0 -> B2 dead after MM4,
    // B1 dead after MM5 -> pack(k+1) runs during/after MM6.
    uint16_t (*const xc)[XPITCH] = reinterpret_cast<uint16_t(*)[XPITCH]>(B1);

    const int tid = threadIdx.x;
    const int lane = tid & 63;
    const int w = tid >> 6, wr = w >> 2, wc = w & 3;   // 2x4 wave grid
    const int lr = lane & 15, lk = lane >> 4;
    const int pr = tid >> 2, pq = tid & 3;             // prefetch: 4 threads/row

    // ---- cross-batch prefetch state: 49 float4 per row, 12(+1 tail) per thread ----
    float4 pf[12]; float4 pfT;

    auto issue_pf = [&](int bbn) {
        const float4* p4 = reinterpret_cast<const float4*>(x + (size_t)bbn * (D * MCOLS)) + 49 * pr;
#pragma unroll
        for (int i = 0; i < 12; ++i) pf[i] = p4[pq + 4 * i];
        if (pq == 0) pfT = p4[48];
    };
    // mean via 4-lane shfl, center exactly in f32, pack bf16, write xc + zero K-pad
    auto pack_pf = [&]() {
        float s = 0.f;
#pragma unroll
        for (int i = 0; i < 12; ++i) s += (pf[i].x + pf[i].y) + (pf[i].z + pf[i].w);
        if (pq == 0) s += (pfT.x + pfT.y) + (pfT.z + pfT.w);
        s += __shfl_xor(s, 1); s += __shfl_xor(s, 2);
        const float m = s * (1.0f / MCOLS);
#pragma unroll
        for (int i = 0; i < 12; ++i)
            *reinterpret_cast<uint64_t*>(&xc[pr][4 * (pq + 4 * i)]) =
                pk64(pf[i].x - m, pf[i].y - m, pf[i].z - m, pf[i].w - m);
        if (pq == 0)
            *reinterpret_cast<uint64_t*>(&xc[pr][192]) =
                pk64(pfT.x - m, pfT.y - m, pfT.z - m, pfT.w - m);
        *reinterpret_cast<uint64_t*>(&xc[pr][MCOLS + 4 * pq]) = 0ull;
        if (pq < 3) *reinterpret_cast<uint64_t*>(&xc[pr][MCOLS + 4 * (pq + 4)]) = 0ull;
    };

    v4f acc[4][2];
    auto zacc = [&]() {
#pragma unroll
        for (int i = 0; i < 4; ++i)
#pragma unroll
            for (int j = 0; j < 2; ++j) acc[i][j] = v4f{0.f, 0.f, 0.f, 0.f};
    };
    auto matmul = [&](const uint16_t* P, const uint16_t* Q) {
        zacc();
#pragma unroll
        for (int kk = 0; kk < 4; ++kk) {
            const int k0 = kk * 32 + lk * 8;
            v8s af[4], bf[2];
#pragma unroll
            for (int i = 0; i < 4; ++i)
                af[i] = *reinterpret_cast<const v8s*>(&P[(64 * wr + 16 * i + lr) * BPITCH + k0]);
#pragma unroll
            for (int j = 0; j < 2; ++j)
                bf[j] = *reinterpret_cast<const v8s*>(&Q[(32 * wc + 16 * j + lr) * BPITCH + k0]);
#pragma unroll
            for (int i = 0; i < 4; ++i)
#pragma unroll
                for (int j = 0; j < 2; ++j)
                    acc[i][j] = __builtin_amdgcn_mfma_f32_16x16x32_bf16(af[i], bf[j], acc[i][j], 0, 0, 0);
        }
    };
    // own-region reload: value quad M[r0..r0+3][c] == one b64 at transposed slot
    auto load_own = [&](const uint16_t* src, int i, int j) -> v4f {
        const int r0 = 64 * wr + 16 * i + 4 * lk;
        const int c  = 32 * wc + 16 * j + lr;
        const uint64_t g = *reinterpret_cast<const uint64_t*>(&src[c * BPITCH + r0]);
        return v4f{unlo((uint32_t)g), unhi((uint32_t)g),
                   unlo((uint32_t)(g >> 32)), unhi((uint32_t)(g >> 32))};
    };
    auto store_tile = [&](uint16_t* dst, int i, int j, const v4f& v) {   // transposed b64
        const int r0 = 64 * wr + 16 * i + 4 * lk;
        const int c  = 32 * wc + 16 * j + lr;
        *reinterpret_cast<uint64_t*>(&dst[c * BPITCH + r0]) = pk64(v[0], v[1], v[2], v[3]);
    };

    // ---- prologue: stage batch (4*blockIdx.x) ----
    issue_pf(4 * blockIdx.x);
    pack_pf();

    for (int it = 0; it < 4; ++it) {
        const int bb = 4 * blockIdx.x + it;
        barrier_nd();                               // xc(bb) ready

        if (it < 3) {                               // issue next batch's loads NOW;
            issue_pf(bb + 1);                       // they stay in flight across all
            __builtin_amdgcn_sched_barrier(0);      // no-drain barriers below
        }

        // ---- cov: covM = xc @ xc^T (centered, K padded to 224) ----
        zacc();
#pragma unroll
        for (int kk = 0; kk < 7; ++kk) {
            const int k0 = kk * 32 + lk * 8;
            v8s af[4], bf[2];
#pragma unroll
            for (int i = 0; i < 4; ++i)
                af[i] = *reinterpret_cast<const v8s*>(&xc[64 * wr + 16 * i + lr][k0]);
#pragma unroll
            for (int j = 0; j < 2; ++j)
                bf[j] = *reinterpret_cast<const v8s*>(&xc[32 * wc + 16 * j + lr][k0]);
#pragma unroll
            for (int i = 0; i < 4; ++i)
#pragma unroll
                for (int j = 0; j < 2; ++j)
                    acc[i][j] = __builtin_amdgcn_mfma_f32_16x16x32_bf16(af[i], bf[j], acc[i][j], 0, 0, 0);
        }

        // trace (C/D layout: col=lane&15, row=(lane>>4)*4+q)
        float tval = 0.f;
        if ((lr >> 2) == lk) {
            const int qq = lr & 3;
#pragma unroll
            for (int i = 0; i < 4; ++i)
#pragma unroll
                for (int j = 0; j < 2; ++j)
                    if (4 * wr + i == 2 * wc + j) tval += acc[i][j][qq];
        }
#pragma unroll
        for (int off = 32; off; off >>= 1) tval += __shfl_down(tval, off);
        if (lane == 0) redbuf[w] = tval;

        // store covM (unnormalized; 1/tr folded into combine scalars below)
#pragma unroll
        for (int i = 0; i < 4; ++i)
#pragma unroll
            for (int j = 0; j < 2; ++j) store_tile(B0, i, j, acc[i][j]);
        barrier_nd();                               // covM + redbuf visible; xc dead

        const float tr = ((redbuf[0] + redbuf[1]) + (redbuf[2] + redbuf[3])) +
                         ((redbuf[4] + redbuf[5]) + (redbuf[6] + redbuf[7]));
        const float inv = 1.0f / tr;
        const float outscale = sqrtf(tr * (1.0f / MCOLS));
        const float s11 = -0.5f * inv * inv, s12 = 1.5f * inv;
        const float s21 = 0.25f * inv;
        const float s41 = -0.5f * inv, s42 = -0.75f * inv;

        // MM1: RY1 = -0.5*inv^2*(C@C) + 1.5*inv*C        -> B1
        matmul(B0, B0);
#pragma unroll
        for (int i = 0; i < 4; ++i)
#pragma unroll
            for (int j = 0; j < 2; ++j) {
                const v4f o = load_own(B0, i, j);
                store_tile(B1, i, j, v4f{s11 * acc[i][j][0] + s12 * o[0],
                                         s11 * acc[i][j][1] + s12 * o[1],
                                         s11 * acc[i][j][2] + s12 * o[2],
                                         s11 * acc[i][j][3] + s12 * o[3]});
            }
        barrier_nd();

        // MM2: RZY1 = 0.25*inv*(C@RY1) - 0.75*RY1        -> B2
        matmul(B0, B1);
#pragma unroll
        for (int i = 0; i < 4; ++i)
#pragma unroll
            for (int j = 0; j < 2; ++j) {
                const v4f o = load_own(B1, i, j);
                store_tile(B2, i, j, v4f{s21 * acc[i][j][0] - 0.75f * o[0],
                                         s21 * acc[i][j][1] - 0.75f * o[1],
                                         s21 * acc[i][j][2] - 0.75f * o[2],
                                         s21 * acc[i][j][3] - 0.75f * o[3]});
            }
        barrier_nd();

        // MM3: RY2 = RY1@RZY1 + 1.5*RY1                  -> B3
        matmul(B1, B2);
#pragma unroll
        for (int i = 0; i < 4; ++i)
#pragma unroll
            for (int j = 0; j < 2; ++j) {
                const v4f o = load_own(B1, i, j);
                store_tile(B3, i, j, v4f{acc[i][j][0] + 1.5f * o[0],
                                         acc[i][j][1] + 1.5f * o[1],
                                         acc[i][j][2] + 1.5f * o[2],
                                         acc[i][j][3] + 1.5f * o[3]});
            }
        barrier_nd();

        // MM4: RZ2 = -0.5*inv*(RZY1@C) - 0.75*inv*C + 1.5*RZY1   -> B1
        matmul(B2, B0);
#pragma unroll
        for (int i = 0; i < 4; ++i)
#pragma unroll
            for (int j = 0; j < 2; ++j) {
                const v4f oc = load_own(B0, i, j);
                const v4f oz = load_own(B2, i, j);
                store_tile(B1, i, j, v4f{s41 * acc[i][j][0] + s42 * oc[0] + 1.5f * oz[0],
                                         s41 * acc[i][j][1] + s42 * oc[1] + 1.5f * oz[1],
                                         s41 * acc[i][j][2] + s42 * oc[2] + 1.5f * oz[2],
                                         s41 * acc[i][j][3] + s42 * oc[3] + 1.5f * oz[3]});
            }
        barrier_nd();

        // MM5: RT2 = RZ2@RY2 + 2.25*RY2                  -> B0
        matmul(B1, B3);
#pragma unroll
        for (int i = 0; i < 4; ++i)
#pragma unroll
            for (int j = 0; j < 2; ++j) {
                const v4f o = load_own(B3, i, j);
                store_tile(B0, i, j, v4f{acc[i][j][0] + 2.25f * o[0],
                                         acc[i][j][1] + 2.25f * o[1],
                                         acc[i][j][2] + 2.25f * o[2],
                                         acc[i][j][3] + 2.25f * o[3]});
            }
        barrier_nd();                              // T2 ready; B1,B2 (=xc region) dead

        // MM6: O = (1.5*RY2 - 0.5*(RY2@RT2)) * outscale ; upper-tri only
        if (!(wr == 1 && wc < 2)) {
            zacc();
#pragma unroll
            for (int kk = 0; kk < 4; ++kk) {
                const int k0 = kk * 32 + lk * 8;
                v8s af[4], bf[2];
#pragma unroll
                for (int i = 0; i < 4; ++i)
                    af[i] = *reinterpret_cast<const v8s*>(&B3[(64 * wr + 16 * i + lr) * BPITCH + k0]);
#pragma unroll
                for (int j = 0; j < 2; ++j)
                    bf[j] = *reinterpret_cast<const v8s*>(&B0[(32 * wc + 16 * j + lr) * BPITCH + k0]);
#pragma unroll
                for (int i = 0; i < 4; ++i)
#pragma unroll
                    for (int j = 0; j < 2; ++j)
                        if (4 * wr + i <= 2 * wc + j)
                            acc[i][j] = __builtin_amdgcn_mfma_f32_16x16x32_bf16(af[i], bf[j], acc[i][j], 0, 0, 0);
            }
            float* ob = out + (size_t)bb * KOUT;
#pragma unroll
            for (int i = 0; i < 4; ++i) {
                const int r0 = 64 * wr + 16 * i + 4 * lk;
#pragma unroll
                for (int j = 0; j < 2; ++j) {
                    const int rb = 4 * wr + i, cb = 2 * wc + j;
                    if (rb > cb) continue;
                    const int c = 32 * wc + 16 * j + lr;
                    const v4f o = load_own(B3, i, j);
                    float vv[4];
#pragma unroll
                    for (int q = 0; q < 4; ++q)
                        vv[q] = (1.5f * o[q] - 0.5f * acc[i][j][q]) * outscale;
                    if (rb < cb) {
#pragma unroll
                        for (int q = 0; q < 4; ++q) {
                            const int r = r0 + q;
                            ob[r * D - (r * (r + 1)) / 2 + c] = vv[q];
                        }
                    } else {
#pragma unroll
                        for (int q = 0; q < 4; ++q) {
                            const int r = r0 + q;
                            if (r <= c) ob[r * D - (r * (r + 1)) / 2 + c] = vv[q];
                        }
                    }
                }
            }
        }
        if (it < 3) pack_pf();                     // xc(bb+1) into B1/B2, overlaps MM6
    }
}

extern "C" void kernel_launch(void* const* d_in, const int* in_sizes, int n_in,
                              void* d_out, int out_size, void* d_ws, size_t ws_size,
                              hipStream_t stream) {
    const float* x = (const float*)d_in[0];
    float* out = (float*)d_out;
    mpncov_kernel<<<dim3(256), dim3(512), 0, stream>>>(x, out);
}